// Round 4
// baseline (190.706 us; speedup 1.0000x reference)
//
#include <hip/hip_runtime.h>
#include <math.h>

#define NB 4096
#define KN 64
#define DIM 128
#define HP 132   // h1 pitch (bf16): 264B/row -> 2-way-max on b128 frag reads (free)

typedef __bf16 bf16;
typedef bf16 bf16x8 __attribute__((ext_vector_type(8)));
typedef bf16 bf16x4 __attribute__((ext_vector_type(4)));
typedef float f32x4 __attribute__((ext_vector_type(4)));

// ---- prep (blocks 0..191): w1T[j][i]=w1[i][j] (bf16), w2T[j2][j1]=w2[j1][j2]
// ---- copy (blocks 192..): passthrough out[0],out[1]; len==0 fallback out[2],out[3]
__global__ void prep_and_copy(const float* __restrict__ w1,
                              const float* __restrict__ w2,
                              bf16* __restrict__ w1T,
                              bf16* __restrict__ w2T,
                              const int* __restrict__ node_idx,
                              const int* __restrict__ neigh_len,
                              const float* __restrict__ emb_v,
                              const float* __restrict__ emb_t,
                              float* __restrict__ out) {
    int blk = blockIdx.x;
    if (blk < 192) {
        int t = blk * 256 + threadIdx.x;
        if (t < 128 * 256) {
            int j = t >> 8, i = t & 255;
            w1T[t] = (bf16)w1[i * 128 + j];
        } else {
            int t2 = t - 128 * 256;
            int j2 = t2 >> 7, j1 = t2 & 127;
            w2T[t2] = (bf16)w2[j1 * 128 + j2];
        }
        return;
    }
    int b = blk - 192;
    int tid = threadIdx.x;
    int m = tid >> 7, j = tid & 127;
    int nd = node_idx[b], len = neigh_len[b];
    const float* emb = m ? emb_t : emb_v;
    float uv = emb[(size_t)nd * DIM + j];
    out[((size_t)m * NB + b) * DIM + j] = uv;
    if (len == 0)
        out[((size_t)(2 + m) * NB + b) * DIM + j] = uv;
}

// ---- main: one block per (b, modality) ----
__global__ __launch_bounds__(256, 4) void graphsage_mfma(
    const int* __restrict__ node_idx,
    const int* __restrict__ neigh_idx,
    const int* __restrict__ neigh_len,
    const float* __restrict__ emb_v,
    const float* __restrict__ emb_t,
    const bf16* __restrict__ w1T,
    const float* __restrict__ b1,
    const bf16* __restrict__ w2T,
    const float* __restrict__ b2,
    const float* __restrict__ w3,
    float* __restrict__ out)
{
    __shared__ bf16  h1_lds[KN][HP];    // 16896 B
    __shared__ float scratch[4][DIM];   // 2048 B: score partials / agg partials
    __shared__ float att_lds[KN];       // 256 B
    __shared__ int   ni_lds[KN];        // 256 B
    __shared__ bf16  u_bf[DIM];         // 256 B
    // ~19.7 KB

    const int b   = blockIdx.x;
    const int m   = blockIdx.y;
    const int tid = threadIdx.x;
    const int len = neigh_len[b];
    if (len == 0) return;   // block-uniform; copy kernel handled outputs

    const float* __restrict__ emb = m ? emb_t : emb_v;

    const int wv = tid >> 6;
    const int ll = tid & 15;
    const int lh = (tid >> 4) & 3;

    if (tid < KN) ni_lds[tid] = neigh_idx[b * KN + tid];
    if (tid < DIM) u_bf[tid] = (bf16)emb[(size_t)node_idx[b] * DIM + tid];
    __syncthreads();   // (1)

    const int nkt = (len + 15) >> 4;   // 1..4 valid k-tiles, block-uniform
    const f32x4 zero4 = {0.f, 0.f, 0.f, 0.f};
    const float4 zf4 = {0.f, 0.f, 0.f, 0.f};

    // ================= GEMM1: H1^T = W1^T @ [N | u_bcast]^T, +b1, relu ========
    {
        // ---- u-part (column-broadcast): one MFMA set, valid for every kk ----
        f32x4 accu[2] = {zero4, zero4};
        {
            #pragma unroll
            for (int ks = 0; ks < 4; ++ks) {
                bf16x8 bu = *(const bf16x8*)&u_bf[ks * 32 + lh * 8];
                bf16x8 a0 = *(const bf16x8*)(w1T + (size_t)(wv * 32 + ll) * 256 + 128 + ks * 32 + lh * 8);
                bf16x8 a1 = *(const bf16x8*)(w1T + (size_t)(wv * 32 + 16 + ll) * 256 + 128 + ks * 32 + lh * 8);
                accu[0] = __builtin_amdgcn_mfma_f32_16x16x32_bf16(a0, bu, accu[0], 0, 0, 0);
                accu[1] = __builtin_amdgcn_mfma_f32_16x16x32_bf16(a1, bu, accu[1], 0, 0, 0);
            }
        }
        float4 b1q0 = *(const float4*)(b1 + wv * 32 + lh * 4);
        float4 b1q1 = *(const float4*)(b1 + wv * 32 + 16 + lh * 4);
        float bq0[4] = {b1q0.x, b1q0.y, b1q0.z, b1q0.w};
        float bq1[4] = {b1q1.x, b1q1.y, b1q1.z, b1q1.w};

        // ---- neighbor part: A-frags (weights) once, B-frags direct from global ----
        bf16x8 af[2][4];
        #pragma unroll
        for (int jt = 0; jt < 2; ++jt)
            #pragma unroll
            for (int ks = 0; ks < 4; ++ks)
                af[jt][ks] = *(const bf16x8*)(w1T + (size_t)(wv * 32 + jt * 16 + ll) * 256 + ks * 32 + lh * 8);

        #pragma unroll
        for (int kt = 0; kt < 4; ++kt) {
            if (kt < nkt) {
                int row = kt * 16 + ll;
                bool vld = row < len;
                const float* src = emb + (size_t)ni_lds[vld ? row : 0] * DIM;
                bf16x8 bfr[4];
                #pragma unroll
                for (int ks = 0; ks < 4; ++ks) {
                    float4 f0 = zf4, f1 = zf4;
                    if (vld) {
                        f0 = ((const float4*)(src + ks * 32 + lh * 8))[0];
                        f1 = ((const float4*)(src + ks * 32 + lh * 8))[1];
                    }
                    bf16x8 v;
                    v[0] = (bf16)f0.x; v[1] = (bf16)f0.y; v[2] = (bf16)f0.z; v[3] = (bf16)f0.w;
                    v[4] = (bf16)f1.x; v[5] = (bf16)f1.y; v[6] = (bf16)f1.z; v[7] = (bf16)f1.w;
                    bfr[ks] = v;
                }
                f32x4 a0 = zero4, a1 = zero4;
                #pragma unroll
                for (int ks = 0; ks < 4; ++ks) {
                    a0 = __builtin_amdgcn_mfma_f32_16x16x32_bf16(af[0][ks], bfr[ks], a0, 0, 0, 0);
                    a1 = __builtin_amdgcn_mfma_f32_16x16x32_bf16(af[1][ks], bfr[ks], a1, 0, 0, 0);
                }
                bf16x4 h0, h1v;
                #pragma unroll
                for (int r = 0; r < 4; ++r) {
                    h0[r]  = (bf16)fmaxf(a0[r] + accu[0][r] + bq0[r], 0.f);
                    h1v[r] = (bf16)fmaxf(a1[r] + accu[1][r] + bq1[r], 0.f);
                }
                *(bf16x4*)&h1_lds[row][wv * 32 + lh * 4]      = h0;
                *(bf16x4*)&h1_lds[row][wv * 32 + 16 + lh * 4] = h1v;
            }
        }
    }
    __syncthreads();   // (2)

    // ================= GEMM2: H2^T = W2^T @ H1^T, fused bias+relu+score ========
    {
        bf16x8 af2[2][4];
        #pragma unroll
        for (int mtl = 0; mtl < 2; ++mtl)
            #pragma unroll
            for (int ks = 0; ks < 4; ++ks)
                af2[mtl][ks] = *(const bf16x8*)(w2T + (size_t)(wv * 32 + mtl * 16 + ll) * 128 + ks * 32 + lh * 8);

        float4 w3a = *(const float4*)(w3 + wv * 32 + lh * 4);
        float4 w3b = *(const float4*)(w3 + wv * 32 + 16 + lh * 4);
        float4 b2a = *(const float4*)(b2 + wv * 32 + lh * 4);
        float4 b2b = *(const float4*)(b2 + wv * 32 + 16 + lh * 4);
        float w3q0[4] = {w3a.x, w3a.y, w3a.z, w3a.w};
        float w3q1[4] = {w3b.x, w3b.y, w3b.z, w3b.w};
        float b2q0[4] = {b2a.x, b2a.y, b2a.z, b2a.w};
        float b2q1[4] = {b2b.x, b2b.y, b2b.z, b2b.w};

        #pragma unroll
        for (int ntk = 0; ntk < 4; ++ntk) {
            if (ntk < nkt) {
                bf16x8 bfr[4];
                #pragma unroll
                for (int ks = 0; ks < 4; ++ks)
                    bfr[ks] = *(const bf16x8*)&h1_lds[ntk * 16 + ll][ks * 32 + lh * 8];
                f32x4 c0 = zero4, c1 = zero4;
                #pragma unroll
                for (int ks = 0; ks < 4; ++ks) {
                    c0 = __builtin_amdgcn_mfma_f32_16x16x32_bf16(af2[0][ks], bfr[ks], c0, 0, 0, 0);
                    c1 = __builtin_amdgcn_mfma_f32_16x16x32_bf16(af2[1][ks], bfr[ks], c1, 0, 0, 0);
                }
                float s = 0.f;
                #pragma unroll
                for (int r = 0; r < 4; ++r) {
                    s = fmaf(fmaxf(c0[r] + b2q0[r], 0.f), w3q0[r], s);
                    s = fmaf(fmaxf(c1[r] + b2q1[r], 0.f), w3q1[r], s);
                }
                s += __shfl_xor(s, 16);
                s += __shfl_xor(s, 32);
                if (lh == 0) scratch[wv][ntk * 16 + ll] = s;
            }
        }
    }
    __syncthreads();   // (3)

    // ===== aggregation prefetch (att-independent) ∥ wave-0 softmax ============
    const int sslice = tid >> 5;          // 0..7; k = sslice + 8q (strided balance)
    const int j0 = (tid & 31) * 4;
    float4 nv[8];
    #pragma unroll
    for (int q = 0; q < 8; ++q) {
        int k = sslice + 8 * q;
        nv[q] = (k < len) ? *(const float4*)(emb + (size_t)ni_lds[k] * DIM + j0) : zf4;
    }

    if (tid < KN) {
        float s = scratch[0][tid] + scratch[1][tid] + scratch[2][tid] + scratch[3][tid];
        float sv = (tid < len) ? s : -INFINITY;
        float mx = sv;
        #pragma unroll
        for (int off = 1; off < 64; off <<= 1) mx = fmaxf(mx, __shfl_xor(mx, off));
        float e = (tid < len) ? __expf(sv - mx) : 0.f;
        float sum = e;
        #pragma unroll
        for (int off = 1; off < 64; off <<= 1) sum += __shfl_xor(sum, off);
        att_lds[tid] = e / sum;
    }
    __syncthreads();   // (4)

    // ===== aggregate (fp32): agg[j] = sum_k att[k] * emb[ni[k]][j] ============
    {
        float ax = 0.f, ay = 0.f, az = 0.f, aw = 0.f;
        #pragma unroll
        for (int q = 0; q < 8; ++q) {
            int k = sslice + 8 * q;
            if (k < len) {
                float a = att_lds[k];
                ax = fmaf(a, nv[q].x, ax);
                ay = fmaf(a, nv[q].y, ay);
                az = fmaf(a, nv[q].z, az);
                aw = fmaf(a, nv[q].w, aw);
            }
        }
        ax += __shfl_xor(ax, 32);
        ay += __shfl_xor(ay, 32);
        az += __shfl_xor(az, 32);
        aw += __shfl_xor(aw, 32);
        if ((tid & 63) < 32) {
            float4 v4 = {ax, ay, az, aw};
            *(float4*)&scratch[wv][j0] = v4;
        }
    }
    __syncthreads();   // (5)
    if (tid < DIM)
        out[((size_t)(2 + m) * NB + b) * DIM + tid] =
            scratch[0][tid] + scratch[1][tid] + scratch[2][tid] + scratch[3][tid];
}

extern "C" void kernel_launch(void* const* d_in, const int* in_sizes, int n_in,
                              void* d_out, int out_size, void* d_ws, size_t ws_size,
                              hipStream_t stream) {
    const int*   node_idx  = (const int*)d_in[0];
    const int*   neigh_idx = (const int*)d_in[1];
    const int*   neigh_len = (const int*)d_in[2];
    const float* emb_v     = (const float*)d_in[3];
    const float* emb_t     = (const float*)d_in[4];
    const float* w1        = (const float*)d_in[5];
    const float* b1        = (const float*)d_in[6];
    const float* w2        = (const float*)d_in[7];
    const float* b2        = (const float*)d_in[8];
    const float* w3        = (const float*)d_in[9];
    float* out = (float*)d_out;

    bf16* w1T = (bf16*)d_ws;                 // 128*256 bf16 = 64 KiB
    bf16* w2T = (bf16*)d_ws + 128 * 256;     // 128*128 bf16 = 32 KiB

    hipLaunchKernelGGL(prep_and_copy, dim3(192 + NB), dim3(256), 0, stream,
                       w1, w2, w1T, w2T, node_idx, neigh_len, emb_v, emb_t, out);
    hipLaunchKernelGGL(graphsage_mfma, dim3(NB, 2), dim3(256), 0, stream,
                       node_idx, neigh_idx, neigh_len, emb_v, emb_t,
                       w1T, b1, w2T, b2, w3, out);
}

// Round 5
// 125.657 us; speedup vs baseline: 1.5177x; 1.5177x over previous
//
#include <hip/hip_runtime.h>
#include <math.h>

#define NB 4096
#define KN 64
#define DIM 128
#define HP 132   // LDS pitch (bf16): 264B/row

typedef __bf16 bf16;
typedef bf16 bf16x8 __attribute__((ext_vector_type(8)));
typedef bf16 bf16x4 __attribute__((ext_vector_type(4)));
typedef float f32x4 __attribute__((ext_vector_type(4)));

// w1T[j][i] = w1[i][j]  (128 x 256 bf16), w2T[j2][j1] = w2[j1][j2] (128 x 128)
__global__ void prep_weights(const float* __restrict__ w1,
                             const float* __restrict__ w2,
                             bf16* __restrict__ w1T,
                             bf16* __restrict__ w2T) {
    int t = blockIdx.x * 256 + threadIdx.x;
    if (t < 128 * 256) {
        int j = t >> 8, i = t & 255;
        w1T[t] = (bf16)w1[i * 128 + j];
    } else {
        int t2 = t - 128 * 256;
        int j2 = t2 >> 7, j1 = t2 & 127;
        w2T[t2] = (bf16)w2[j1 * 128 + j2];
    }
}

__global__ __launch_bounds__(256, 4) void graphsage_mfma(
    const int* __restrict__ node_idx,
    const int* __restrict__ neigh_idx,
    const int* __restrict__ neigh_len,
    const float* __restrict__ emb_v,
    const float* __restrict__ emb_t,
    const bf16* __restrict__ w1T,
    const float* __restrict__ b1,
    const bf16* __restrict__ w2T,
    const float* __restrict__ b2,
    const float* __restrict__ w3,
    float* __restrict__ out)
{
    __shared__ bf16  n_lds[KN][HP];      // 16896 B
    __shared__ bf16  h1_lds[KN][HP];     // 16896 B
    __shared__ float s_lds[2][4][KN];    // 2048 B (per-modality score partials)
    __shared__ int   ni_lds[KN];         // 256 B
    __shared__ bf16  u_bf[2][DIM];       // 512 B
    // total 36608 B -> 4 blocks/CU

    const int b   = blockIdx.x;
    const int tid = threadIdx.x;
    const int len = neigh_len[b];
    const int nd  = node_idx[b];

    // ---- pre-phase: passthrough for both modalities; len==0 fallback ----
    {
        int mp = tid >> 7, j = tid & 127;
        const float* emb = mp ? emb_t : emb_v;
        float uv = emb[(size_t)nd * DIM + j];
        out[((size_t)mp * NB + b) * DIM + j] = uv;
        if (len == 0)
            out[((size_t)(2 + mp) * NB + b) * DIM + j] = uv;
        else
            u_bf[mp][j] = (bf16)uv;
    }
    if (len == 0) return;   // block-uniform
    if (tid < KN) ni_lds[tid] = neigh_idx[b * KN + tid];
    __syncthreads();   // B0: ni, u_bf ready

    const int wv = tid >> 6;
    const int ll = tid & 15;
    const int lh = (tid >> 4) & 3;
    const int l  = tid & 63;
    const int nkt = (len + 15) >> 4;   // 1..4, block-uniform
    const int lim = nkt * 16;
    const f32x4 zero4 = {0.f, 0.f, 0.f, 0.f};

    #pragma unroll
    for (int m = 0; m < 2; ++m) {
        const float* __restrict__ emb = m ? emb_t : emb_v;

        // ---- bulk gather: valid neighbor rows -> bf16 LDS (zero-fill pad) ----
        for (int c = tid; c < lim * 16; c += 256) {
            int r = c >> 4, c8 = c & 15;
            bf16x8 v;
            if (r < len) {
                const float* src = emb + (size_t)ni_lds[r] * DIM + c8 * 8;
                float4 f0 = ((const float4*)src)[0];
                float4 f1 = ((const float4*)src)[1];
                v[0] = (bf16)f0.x; v[1] = (bf16)f0.y; v[2] = (bf16)f0.z; v[3] = (bf16)f0.w;
                v[4] = (bf16)f1.x; v[5] = (bf16)f1.y; v[6] = (bf16)f1.z; v[7] = (bf16)f1.w;
            } else {
                #pragma unroll
                for (int q = 0; q < 8; ++q) v[q] = (bf16)0.f;
            }
            *(bf16x8*)&n_lds[r][c8 * 8] = v;
        }
        __syncthreads();   // B1: n_lds ready

        // ---- GEMM1 (j-split): H1^T = W1^T @ [N | u]^T, +b1, relu ----
        {
            // u contribution (broadcast-B MFMA; rows j1 of jt=0 / jt=1)
            f32x4 accu0 = zero4, accu1 = zero4;
            #pragma unroll
            for (int ks = 0; ks < 4; ++ks) {
                bf16x8 bu = *(const bf16x8*)&u_bf[m][ks * 32 + lh * 8];
                bf16x8 a0 = *(const bf16x8*)(w1T + (size_t)(wv * 32 + ll) * 256 + 128 + ks * 32 + lh * 8);
                bf16x8 a1 = *(const bf16x8*)(w1T + (size_t)(wv * 32 + 16 + ll) * 256 + 128 + ks * 32 + lh * 8);
                accu0 = __builtin_amdgcn_mfma_f32_16x16x32_bf16(a0, bu, accu0, 0, 0, 0);
                accu1 = __builtin_amdgcn_mfma_f32_16x16x32_bf16(a1, bu, accu1, 0, 0, 0);
            }
            float4 b1q0 = *(const float4*)(b1 + wv * 32 + lh * 4);
            float4 b1q1 = *(const float4*)(b1 + wv * 32 + 16 + lh * 4);
            float ba0[4] = {b1q0.x, b1q0.y, b1q0.z, b1q0.w};
            float ba1[4] = {b1q1.x, b1q1.y, b1q1.z, b1q1.w};

            bf16x8 af0[4], af1[4];
            #pragma unroll
            for (int ks = 0; ks < 4; ++ks) {
                af0[ks] = *(const bf16x8*)(w1T + (size_t)(wv * 32 + ll) * 256 + ks * 32 + lh * 8);
                af1[ks] = *(const bf16x8*)(w1T + (size_t)(wv * 32 + 16 + ll) * 256 + ks * 32 + lh * 8);
            }

            #pragma unroll
            for (int kt = 0; kt < 4; ++kt) {
                if (kt < nkt) {
                    bf16x8 bfr[4];
                    #pragma unroll
                    for (int ks = 0; ks < 4; ++ks)
                        bfr[ks] = *(const bf16x8*)&n_lds[kt * 16 + ll][ks * 32 + lh * 8];
                    f32x4 a0 = accu0, a1 = accu1;
                    #pragma unroll
                    for (int ks = 0; ks < 4; ++ks) {
                        a0 = __builtin_amdgcn_mfma_f32_16x16x32_bf16(af0[ks], bfr[ks], a0, 0, 0, 0);
                        a1 = __builtin_amdgcn_mfma_f32_16x16x32_bf16(af1[ks], bfr[ks], a1, 0, 0, 0);
                    }
                    bf16x4 h0, h1v;
                    #pragma unroll
                    for (int r = 0; r < 4; ++r) {
                        h0[r]  = (bf16)fmaxf(a0[r] + ba0[r], 0.f);
                        h1v[r] = (bf16)fmaxf(a1[r] + ba1[r], 0.f);
                    }
                    *(bf16x4*)&h1_lds[kt * 16 + ll][wv * 32 + lh * 4]      = h0;
                    *(bf16x4*)&h1_lds[kt * 16 + ll][wv * 32 + 16 + lh * 4] = h1v;
                }
            }
        }
        __syncthreads();   // B2: h1 ready

        // ---- GEMM2 (j2-split): fused bias+relu+score partials ----
        {
            bf16x8 af20[4], af21[4];
            #pragma unroll
            for (int ks = 0; ks < 4; ++ks) {
                af20[ks] = *(const bf16x8*)(w2T + (size_t)(wv * 32 + ll) * 128 + ks * 32 + lh * 8);
                af21[ks] = *(const bf16x8*)(w2T + (size_t)(wv * 32 + 16 + ll) * 128 + ks * 32 + lh * 8);
            }
            float4 w3a = *(const float4*)(w3 + wv * 32 + lh * 4);
            float4 w3b = *(const float4*)(w3 + wv * 32 + 16 + lh * 4);
            float4 b2a = *(const float4*)(b2 + wv * 32 + lh * 4);
            float4 b2b = *(const float4*)(b2 + wv * 32 + 16 + lh * 4);
            float w3q0[4] = {w3a.x, w3a.y, w3a.z, w3a.w};
            float w3q1[4] = {w3b.x, w3b.y, w3b.z, w3b.w};
            float b2q0[4] = {b2a.x, b2a.y, b2a.z, b2a.w};
            float b2q1[4] = {b2b.x, b2b.y, b2b.z, b2b.w};

            #pragma unroll
            for (int ntk = 0; ntk < 4; ++ntk) {
                if (ntk < nkt) {
                    bf16x8 bfr[4];
                    #pragma unroll
                    for (int ks = 0; ks < 4; ++ks)
                        bfr[ks] = *(const bf16x8*)&h1_lds[ntk * 16 + ll][ks * 32 + lh * 8];
                    f32x4 c0 = zero4, c1 = zero4;
                    #pragma unroll
                    for (int ks = 0; ks < 4; ++ks) {
                        c0 = __builtin_amdgcn_mfma_f32_16x16x32_bf16(af20[ks], bfr[ks], c0, 0, 0, 0);
                        c1 = __builtin_amdgcn_mfma_f32_16x16x32_bf16(af21[ks], bfr[ks], c1, 0, 0, 0);
                    }
                    float s = 0.f;
                    #pragma unroll
                    for (int r = 0; r < 4; ++r) {
                        s = fmaf(fmaxf(c0[r] + b2q0[r], 0.f), w3q0[r], s);
                        s = fmaf(fmaxf(c1[r] + b2q1[r], 0.f), w3q1[r], s);
                    }
                    s += __shfl_xor(s, 16);
                    s += __shfl_xor(s, 32);
                    if (lh == 0) s_lds[m][wv][ntk * 16 + ll] = s;
                }
            }
        }
        __syncthreads();   // B3: score partials ready

        // ---- softmax: per-wave redundant, att stays in a register (lane = k) ----
        float sc = s_lds[m][0][l] + s_lds[m][1][l] + s_lds[m][2][l] + s_lds[m][3][l];
        float sv = (l < len) ? sc : -1e30f;
        float mx = sv;
        #pragma unroll
        for (int off = 1; off < 64; off <<= 1) mx = fmaxf(mx, __shfl_xor(mx, off));
        float e = (l < len) ? __expf(sv - mx) : 0.f;
        float sm = e;
        #pragma unroll
        for (int off = 1; off < 64; off <<= 1) sm += __shfl_xor(sm, off);
        float attv = e / sm;

        // ---- aggregate from n_lds: wave owns 32 j-cols; shfl-broadcast att ----
        {
            int j0 = wv * 32 + (l & 7) * 4;
            int slice = l >> 3;
            float ax = 0.f, ay = 0.f, az = 0.f, aw = 0.f;
            #pragma unroll
            for (int q = 0; q < 8; ++q) {
                int k = slice + 8 * q;
                float ak = __shfl(attv, k);
                if (k < len) {
                    bf16x4 nv = *(const bf16x4*)&n_lds[k][j0];
                    ax = fmaf(ak, (float)nv[0], ax);
                    ay = fmaf(ak, (float)nv[1], ay);
                    az = fmaf(ak, (float)nv[2], az);
                    aw = fmaf(ak, (float)nv[3], aw);
                }
            }
            ax += __shfl_xor(ax, 8);  ax += __shfl_xor(ax, 16);  ax += __shfl_xor(ax, 32);
            ay += __shfl_xor(ay, 8);  ay += __shfl_xor(ay, 16);  ay += __shfl_xor(ay, 32);
            az += __shfl_xor(az, 8);  az += __shfl_xor(az, 16);  az += __shfl_xor(az, 32);
            aw += __shfl_xor(aw, 8);  aw += __shfl_xor(aw, 16);  aw += __shfl_xor(aw, 32);
            if (l < 8) {
                float4 v4 = {ax, ay, az, aw};
                *(float4*)(out + ((size_t)(2 + m) * NB + b) * DIM + j0) = v4;
            }
        }
        if (m == 0) __syncthreads();   // B4: protect n_lds/h1 before m=1 gather
    }
}

extern "C" void kernel_launch(void* const* d_in, const int* in_sizes, int n_in,
                              void* d_out, int out_size, void* d_ws, size_t ws_size,
                              hipStream_t stream) {
    const int*   node_idx  = (const int*)d_in[0];
    const int*   neigh_idx = (const int*)d_in[1];
    const int*   neigh_len = (const int*)d_in[2];
    const float* emb_v     = (const float*)d_in[3];
    const float* emb_t     = (const float*)d_in[4];
    const float* w1        = (const float*)d_in[5];
    const float* b1        = (const float*)d_in[6];
    const float* w2        = (const float*)d_in[7];
    const float* b2        = (const float*)d_in[8];
    const float* w3        = (const float*)d_in[9];
    float* out = (float*)d_out;

    bf16* w1T = (bf16*)d_ws;                 // 128*256 bf16 = 64 KiB
    bf16* w2T = (bf16*)d_ws + 128 * 256;     // 128*128 bf16 = 32 KiB

    hipLaunchKernelGGL(prep_weights, dim3(192), dim3(256), 0, stream, w1, w2, w1T, w2T);
    hipLaunchKernelGGL(graphsage_mfma, dim3(NB), dim3(256), 0, stream,
                       node_idx, neigh_idx, neigh_len, emb_v, emb_t,
                       w1T, b1, w2T, b2, w3, out);
}